// Round 1
// baseline (456.672 us; speedup 1.0000x reference)
//
#include <hip/hip_runtime.h>

// Problem constants (from setup_inputs): x[16,64,4096], emb[1024,64]
constexpr int B = 16, D = 64, T = 4096, E = 1024;
constexpr int NROW = B * T;            // 65536 rows of dim D
constexpr float DECAYF = 0.99f;
constexpr float OMDF   = 0.01f;        // 1 - decay (f32-rounds same as ref)
constexpr float EPSF   = 1e-5f;

// ws layout (floats): e2[1024] | counts[1024] | embed_sum[65536] | norm[1024]
// d_out layout (floats, ref return order):
//   embed_idx [B,T,D]     @ 0        (4194304)
//   embed_idx_qx [B,D,T]  @ 4194304  (4194304)
//   quantized_idx [B,T]   @ 8388608  (65536, stored as float)
//   new_embedding [E,D]   @ 8454144  (65536)
//   new_ema_size [E]      @ 8519680  (1024)
//   new_ema_w [D,E]       @ 8520704  (65536)

// ---- prep: e2[e] = numpy-pairwise sum of emb[e,:]^2 ; zero count/embed_sum ----
__global__ __launch_bounds__(256) void prep_kernel(const float* __restrict__ emb,
                                                   float* __restrict__ ws) {
  int tid = blockIdx.x * 256 + threadIdx.x;
  if (tid < E) {
    #pragma clang fp contract(off)
    const float* ep = emb + tid * D;
    float r[8];
    #pragma unroll
    for (int j = 0; j < 8; ++j) { float v = ep[j]; r[j] = v * v; }
    #pragma unroll
    for (int k = 1; k < 8; ++k) {
      #pragma unroll
      for (int j = 0; j < 8; ++j) { float v = ep[8 * k + j]; r[j] += v * v; }
    }
    ws[tid] = ((r[0] + r[1]) + (r[2] + r[3])) + ((r[4] + r[5]) + (r[6] + r[7]));
  } else if (tid < 1024 + 1024 + 65536) {
    ws[tid] = 0.0f;  // counts + embed_sum
  }
}

// ---- assign: per-row argmin over E, outputs embed_idx/qx/idx, EMA atomics ----
__global__ __launch_bounds__(256) void assign_kernel(
    const float* __restrict__ x, const float* __restrict__ emb,
    const float* __restrict__ e2s, float* __restrict__ counts,
    float* __restrict__ embed_sum, float* __restrict__ out_embed_idx,
    float* __restrict__ out_qx, float* __restrict__ out_idx) {
  const int lane = threadIdx.x & 63;
  const int wave = threadIdx.x >> 6;
  const int row  = blockIdx.x * 64 + lane;       // 64 rows per block
  const int b = row >> 12;                       // T = 4096
  const int t = row & (T - 1);
  const float* xrow = x + (size_t)b * D * T + t;

  float xv[64];
  #pragma unroll
  for (int d = 0; d < D; ++d) xv[d] = xrow[(size_t)d * T];  // coalesced per d

  // x2: replicate numpy pairwise sum (n=64: 8 strided accumulators)
  float x2;
  {
    #pragma clang fp contract(off)
    float r[8];
    #pragma unroll
    for (int j = 0; j < 8; ++j) r[j] = xv[j] * xv[j];
    #pragma unroll
    for (int k = 1; k < 8; ++k) {
      #pragma unroll
      for (int j = 0; j < 8; ++j) r[j] += xv[8 * k + j] * xv[8 * k + j];
    }
    x2 = ((r[0] + r[1]) + (r[2] + r[3])) + ((r[4] + r[5]) + (r[6] + r[7]));
  }

  // each wave scans 256 codewords; e-base made provably wave-uniform -> s_load
  const int e0 = __builtin_amdgcn_readfirstlane(wave << 8);
  float best = 3.4e38f;
  int bidx = 0;
  for (int ei = 0; ei < 256; ++ei) {
    const int e = e0 + ei;
    const float* ep = emb + e * D;   // wave-uniform address -> scalar loads
    float d0 = 0.f, d1 = 0.f, d2 = 0.f, d3 = 0.f;
    #pragma unroll
    for (int k = 0; k < 16; ++k) {
      d0 = __builtin_fmaf(xv[4 * k + 0], ep[4 * k + 0], d0);
      d1 = __builtin_fmaf(xv[4 * k + 1], ep[4 * k + 1], d1);
      d2 = __builtin_fmaf(xv[4 * k + 2], ep[4 * k + 2], d2);
      d3 = __builtin_fmaf(xv[4 * k + 3], ep[4 * k + 3], d3);
    }
    float dot = (d0 + d1) + (d2 + d3);
    float sc = __builtin_fmaf(-2.0f, dot, e2s[e]);  // fl(e2 - 2*dot)
    float q = sc + x2;                              // fl(... + x2): ref quantization
    if (q < best) { best = q; bidx = e; }           // strict < : first-index ties
  }

  // merge the 4 wave-chunks (ascending e order => strict < keeps lowest index)
  __shared__ float s_q[4][64];
  __shared__ int   s_i[4][64];
  s_q[wave][lane] = best;
  s_i[wave][lane] = bidx;
  __syncthreads();
  float q = s_q[0][lane];
  int bi = s_i[0][lane];
  #pragma unroll
  for (int w = 1; w < 4; ++w) {
    float q2 = s_q[w][lane]; int i2 = s_i[w][lane];
    if (q2 < q) { q = q2; bi = i2; }
  }

  if (wave == 0) {
    out_idx[row] = (float)bi;
    atomicAdd(&counts[bi], 1.0f);
  }

  // epilogue: wave w handles d in [w*16, w*16+16) with compile-time xv indices
  const float* ebest = emb + bi * D;
  float* qx_base = out_qx + (size_t)b * D * T + t;
  float* ei_base = out_embed_idx + (size_t)row * D;

#define EPILOGUE(W)                                                   \
  {                                                                   \
    _Pragma("unroll")                                                 \
    for (int k = 0; k < 16; ++k) {                                    \
      const int d = (W) * 16 + k;                                     \
      float ev = ebest[d];                                            \
      float xd = xv[d];                                               \
      float diff = ev - xd;        /* fl(e - x)      */               \
      float qxv = xd + diff;       /* fl(x + fl(e-x))*/               \
      qx_base[(size_t)d * T] = qxv;                                   \
      ei_base[d] = ev;                                                \
      atomicAdd(&embed_sum[d * E + bi], xd);                          \
    }                                                                 \
  }
  if (wave == 0) EPILOGUE(0)
  else if (wave == 1) EPILOGUE(1)
  else if (wave == 2) EPILOGUE(2)
  else EPILOGUE(3)
#undef EPILOGUE
}

// ---- finalize_a: ema_size update + normalization (1 block of 1024) ----
__global__ __launch_bounds__(1024) void finalize_a(
    const float* __restrict__ ema_size, const float* __restrict__ counts,
    float* __restrict__ norm, float* __restrict__ out_ema_size) {
  const int e = threadIdx.x;
  float ns = DECAYF * ema_size[e] + OMDF * counts[e];
  __shared__ float red[1024];
  red[e] = ns;
  __syncthreads();
  for (int s = 512; s > 0; s >>= 1) {
    if (e < s) red[e] += red[e + s];
    __syncthreads();
  }
  float n = red[0];
  float v = ((ns + EPSF) / (n + (float)E * EPSF)) * n;
  out_ema_size[e] = v;
  norm[e] = v;
}

// ---- finalize_b: new_ema_w + new_embedding ----
__global__ __launch_bounds__(256) void finalize_b(
    const float* __restrict__ ema_w, const float* __restrict__ embed_sum,
    const float* __restrict__ norm, float* __restrict__ out_embedding,
    float* __restrict__ out_ema_w) {
  int i = blockIdx.x * 256 + threadIdx.x;  // 0 .. 65535 ; i = d*E + e
  int d = i >> 10;
  int e = i & (E - 1);
  float w = DECAYF * ema_w[i] + OMDF * embed_sum[i];
  out_ema_w[i] = w;
  out_embedding[e * D + d] = w / norm[e];
}

extern "C" void kernel_launch(void* const* d_in, const int* in_sizes, int n_in,
                              void* d_out, int out_size, void* d_ws, size_t ws_size,
                              hipStream_t stream) {
  const float* x        = (const float*)d_in[0];
  const float* emb      = (const float*)d_in[1];
  const float* ema_size = (const float*)d_in[2];
  const float* ema_w    = (const float*)d_in[3];

  float* out = (float*)d_out;
  float* o_embed_idx = out;                // [B,T,D]
  float* o_qx        = out + 4194304;      // [B,D,T]
  float* o_idx       = out + 8388608;      // [B,T]
  float* o_embedding = out + 8454144;      // [E,D]
  float* o_ema_size  = out + 8519680;      // [E]
  float* o_ema_w     = out + 8520704;      // [D,E]

  float* ws      = (float*)d_ws;
  float* w_e2    = ws;             // 1024
  float* w_counts= ws + 1024;      // 1024
  float* w_esum  = ws + 2048;      // 65536
  float* w_norm  = ws + 67584;     // 1024

  prep_kernel<<<264, 256, 0, stream>>>(emb, ws);
  assign_kernel<<<NROW / 64, 256, 0, stream>>>(x, emb, w_e2, w_counts, w_esum,
                                               o_embed_idx, o_qx, o_idx);
  finalize_a<<<1, 1024, 0, stream>>>(ema_size, w_counts, w_norm, o_ema_size);
  finalize_b<<<E * D / 256, 256, 0, stream>>>(ema_w, w_esum, w_norm,
                                              o_embedding, o_ema_w);
}